// Round 1
// baseline (253.425 us; speedup 1.0000x reference)
//
#include <hip/hip_runtime.h>
#include <hip/hip_bf16.h>

#define EPSV 1e-5f

constexpr int Bn = 16;    // batch
constexpr int Nn = 512;   // nodes
constexpr int Fn = 64;    // features
constexpr int Aout = 512; // actions (output classes)

// ---------------------------------------------------------------------------
// adjs = adjs0 + adjs1 + adjs2 (elementwise, float4)
// ---------------------------------------------------------------------------
__launch_bounds__(256)
__global__ void add3_kernel(const float4* __restrict__ a0,
                            const float4* __restrict__ a1,
                            const float4* __restrict__ a2,
                            float4* __restrict__ o, int n4) {
  int i = blockIdx.x * 256 + threadIdx.x;
  if (i < n4) {
    float4 x = a0[i], y = a1[i], z = a2[i];
    float4 r;
    r.x = x.x + y.x + z.x;
    r.y = x.y + y.y + z.y;
    r.z = x.z + y.z + z.z;
    r.w = x.w + y.w + z.w;
    o[i] = r;
  }
}

// ---------------------------------------------------------------------------
// C[z][b] (Nn x Fn) = (Cin[z][b]?) + A[z][b] (Nn x Nn) @ X[z][b or shared] (Nn x Fn)
// optional fused BN(+ReLU) over rows n (axis=1 of [B,N,F]).
// Tile: 32 rows x 64 cols, K-tile 64, 128 threads, 4x4 micro-tile per thread.
// ---------------------------------------------------------------------------
struct GemmNFArgs {
  const float* A[3];
  const float* X[3];
  const float* Cin[3];
  float* C[3];
  long long xbs;  // batch stride of X (0 for shared weight)
  const float* bn_mean;
  const float* bn_var;
  const float* bn_gamma;
  const float* bn_beta;
};

__launch_bounds__(128)
__global__ void gemm_nf_kernel(GemmNFArgs args) {
  const int z = blockIdx.z;
  const int b = blockIdx.y;
  const int row0 = blockIdx.x * 32;
  const float* __restrict__ Ab = args.A[z] + (size_t)b * Nn * Nn;
  const float* __restrict__ Xb = args.X[z] + (size_t)b * args.xbs;
  float* __restrict__ Cb = args.C[z] + ((size_t)b * Nn + row0) * Fn;

  __shared__ float AsT[64][36];  // transposed A tile, padded (36: 16B-aligned rows, bank-spread)
  __shared__ float Xs[64][64];

  const int t = threadIdx.x;
  const int tx = t & 15;  // 16 -> 4 cols each
  const int ty = t >> 4;  // 8  -> 4 rows each

  float acc[4][4] = {};

  for (int k0 = 0; k0 < Nn; k0 += 64) {
    // A tile: 32 rows x 64 k, stored transposed AsT[k][row]
    {
      const int r = t >> 2;  // 0..31
      const int q = t & 3;   // 0..3
      const float* Ap = Ab + (size_t)(row0 + r) * Nn + k0;
#pragma unroll
      for (int rep = 0; rep < 4; ++rep) {
        const int kl = q * 4 + rep * 16;
        float4 v = *(const float4*)(Ap + kl);
        AsT[kl + 0][r] = v.x;
        AsT[kl + 1][r] = v.y;
        AsT[kl + 2][r] = v.z;
        AsT[kl + 3][r] = v.w;
      }
    }
    // X tile: 64 k-rows x 64 f
    {
      const int c4 = t & 15;
      const int kr0 = t >> 4;  // 0..7
#pragma unroll
      for (int rep = 0; rep < 8; ++rep) {
        const int kr = kr0 + rep * 8;
        *(float4*)&Xs[kr][c4 * 4] =
            *(const float4*)(Xb + (size_t)(k0 + kr) * Fn + c4 * 4);
      }
    }
    __syncthreads();
#pragma unroll
    for (int kk = 0; kk < 64; ++kk) {
      float4 a4 = *(const float4*)&AsT[kk][ty * 4];
      float4 x4 = *(const float4*)&Xs[kk][tx * 4];
      float av[4] = {a4.x, a4.y, a4.z, a4.w};
      float xv[4] = {x4.x, x4.y, x4.z, x4.w};
#pragma unroll
      for (int i = 0; i < 4; ++i)
#pragma unroll
        for (int j = 0; j < 4; ++j) acc[i][j] = fmaf(av[i], xv[j], acc[i][j]);
    }
    __syncthreads();
  }

  const bool has_cin = args.Cin[z] != nullptr;
  const bool has_bn = args.bn_mean != nullptr;
#pragma unroll
  for (int i = 0; i < 4; ++i) {
    const int n = row0 + ty * 4 + i;
    float v0 = acc[i][0], v1 = acc[i][1], v2 = acc[i][2], v3 = acc[i][3];
    if (has_cin) {
      const float4 ci =
          *(const float4*)(args.Cin[z] + ((size_t)b * Nn + n) * Fn + tx * 4);
      v0 += ci.x;
      v1 += ci.y;
      v2 += ci.z;
      v3 += ci.w;
    }
    if (has_bn) {
      const float sc = rsqrtf(args.bn_var[n] + EPSV) * args.bn_gamma[n];
      const float mu = args.bn_mean[n];
      const float bt = args.bn_beta[n];
      v0 = fmaxf(fmaf(v0 - mu, sc, bt), 0.f);
      v1 = fmaxf(fmaf(v1 - mu, sc, bt), 0.f);
      v2 = fmaxf(fmaf(v2 - mu, sc, bt), 0.f);
      v3 = fmaxf(fmaf(v3 - mu, sc, bt), 0.f);
    }
    float4 o = {v0, v1, v2, v3};
    *(float4*)(Cb + (size_t)(ty * 4 + i) * Fn + tx * 4) = o;
  }
}

// ---------------------------------------------------------------------------
// h_next = relu(BN_l( h@W3l + b_l + P0@W0l + P1@W1l + P2@W2l ))
// M = B*N = 8192 rows; 4 rows/block, 256 threads (one output each per f).
// ---------------------------------------------------------------------------
__launch_bounds__(256)
__global__ void layer_fuse_kernel(const float* __restrict__ h,
                                  const float* __restrict__ P0,
                                  const float* __restrict__ P1,
                                  const float* __restrict__ P2,
                                  const float* __restrict__ W3,
                                  const float* __restrict__ W0,
                                  const float* __restrict__ W1,
                                  const float* __restrict__ W2,
                                  const float* __restrict__ bias,
                                  const float* __restrict__ mean,
                                  const float* __restrict__ var,
                                  const float* __restrict__ gamma,
                                  const float* __restrict__ beta,
                                  float* __restrict__ out) {
  const int row0 = blockIdx.x * 4;
  __shared__ float ins[4][4][64];  // [mat][row][k]
  const int t = threadIdx.x;
  {
    const int mat = t >> 6;
    const int r = (t >> 4) & 3;
    const int c4 = t & 15;
    const float* src = (mat == 0) ? h : (mat == 1) ? P0 : (mat == 2) ? P1 : P2;
    *(float4*)&ins[mat][r][c4 * 4] =
        *(const float4*)(src + (size_t)(row0 + r) * Fn + c4 * 4);
  }
  __syncthreads();
  const int f = t & 63;
  const int r = t >> 6;
  const int row = row0 + r;
  const int n = row & (Nn - 1);
  float acc = bias[f];
  const float* Ws[4] = {W3, W0, W1, W2};
#pragma unroll
  for (int mat = 0; mat < 4; ++mat) {
    const float* __restrict__ W = Ws[mat];
#pragma unroll 8
    for (int kk = 0; kk < 64; ++kk)
      acc = fmaf(ins[mat][r][kk], W[kk * 64 + f], acc);
  }
  const float sc = rsqrtf(var[n] + EPSV) * gamma[n];
  float v = fmaf(acc - mean[n], sc, beta[n]);
  out[(size_t)row * Fn + f] = v > 0.f ? v : 0.f;
}

// ---------------------------------------------------------------------------
// graph head: sum over n -> BN+ReLU (per f) -> FC (512) -> softmax. 1 block/batch.
// ---------------------------------------------------------------------------
__launch_bounds__(256)
__global__ void graph_head_kernel(const float* __restrict__ h3,
                                  const float* __restrict__ gmean,
                                  const float* __restrict__ gvar,
                                  const float* __restrict__ ggamma,
                                  const float* __restrict__ gbeta,
                                  const float* __restrict__ fc_w,
                                  const float* __restrict__ fc_b,
                                  float* __restrict__ out) {
  const int b = blockIdx.x;
  const int t = threadIdx.x;
  __shared__ float part[4][64];
  __shared__ float gh[64];
  __shared__ float red[256];

  const int f = t & 63;
  const int chunk = t >> 6;
  const float* hp = h3 + (size_t)b * Nn * Fn;
  float s = 0.f;
  for (int i = 0; i < Nn / 4; ++i)
    s += hp[(size_t)(chunk * (Nn / 4) + i) * Fn + f];
  part[chunk][f] = s;
  __syncthreads();
  if (t < 64) {
    float sum = part[0][t] + part[1][t] + part[2][t] + part[3][t];
    float sc = rsqrtf(gvar[t] + EPSV) * ggamma[t];
    float v = fmaf(sum - gmean[t], sc, gbeta[t]);
    gh[t] = v > 0.f ? v : 0.f;
  }
  __syncthreads();

  float lg[2];
#pragma unroll
  for (int rep = 0; rep < 2; ++rep) {
    const int a = t + rep * 256;
    const float* __restrict__ w = fc_w + (size_t)a * Fn;
    float acc = fc_b[a];
#pragma unroll 8
    for (int kk = 0; kk < 64; ++kk) acc = fmaf(gh[kk], w[kk], acc);
    lg[rep] = acc;
  }
  // softmax over 512 logits (2 per thread)
  red[t] = fmaxf(lg[0], lg[1]);
  __syncthreads();
  for (int off = 128; off > 0; off >>= 1) {
    if (t < off) red[t] = fmaxf(red[t], red[t + off]);
    __syncthreads();
  }
  const float mx = red[0];
  __syncthreads();
  const float e0 = __expf(lg[0] - mx), e1 = __expf(lg[1] - mx);
  red[t] = e0 + e1;
  __syncthreads();
  for (int off = 128; off > 0; off >>= 1) {
    if (t < off) red[t] += red[t + off];
    __syncthreads();
  }
  const float inv = 1.f / red[0];
  out[(size_t)b * Aout + t] = e0 * inv;
  out[(size_t)b * Aout + t + 256] = e1 * inv;
}

// ---------------------------------------------------------------------------
extern "C" void kernel_launch(void* const* d_in, const int* in_sizes, int n_in,
                              void* d_out, int out_size, void* d_ws,
                              size_t ws_size, hipStream_t stream) {
  (void)in_sizes; (void)n_in; (void)out_size; (void)ws_size;
  const float* hs_init = (const float*)d_in[0];
  const float* adjs0 = (const float*)d_in[1];
  const float* adjs1 = (const float*)d_in[2];
  const float* adjs2 = (const float*)d_in[3];
  const float* W_init = (const float*)d_in[4];
  const float* W0 = (const float*)d_in[5];
  const float* W1 = (const float*)d_in[6];
  const float* W2 = (const float*)d_in[7];
  const float* W3 = (const float*)d_in[8];
  const float* bvec = (const float*)d_in[9];
  const float* fc1_w = (const float*)d_in[10];
  const float* fc1_b = (const float*)d_in[11];
  const float* bn_init_mean = (const float*)d_in[12];
  const float* bn_init_var = (const float*)d_in[13];
  const float* bn_init_gamma = (const float*)d_in[14];
  const float* bn_init_beta = (const float*)d_in[15];
  const float* bn_layer_mean = (const float*)d_in[16];
  const float* bn_layer_var = (const float*)d_in[17];
  const float* bn_layer_gamma = (const float*)d_in[18];
  const float* bn_layer_beta = (const float*)d_in[19];
  const float* bn_graph_mean = (const float*)d_in[20];
  const float* bn_graph_var = (const float*)d_in[21];
  const float* bn_graph_gamma = (const float*)d_in[22];
  const float* bn_graph_beta = (const float*)d_in[23];

  const size_t BNN = (size_t)Bn * Nn * Nn;  // 4,194,304
  const size_t BNF = (size_t)Bn * Nn * Fn;  // 524,288

  float* ws = (float*)d_ws;
  float* adjs = ws;       ws += BNN;
  float* h0 = ws;         ws += BNF;
  float* h1 = ws;         ws += BNF;
  float* h2 = ws;         ws += BNF;
  float* h3 = ws;         ws += BNF;
  float* g0 = ws;         ws += BNF;
  float* g1 = ws;         ws += BNF;
  float* g2 = ws;         ws += BNF;
  float* Pa0 = ws;        ws += BNF;
  float* Pa1 = ws;        ws += BNF;
  float* Pa2 = ws;        ws += BNF;
  float* Pb0 = ws;        ws += BNF;
  float* Pb1 = ws;        ws += BNF;
  float* Pb2 = ws;        ws += BNF;

  // 1) adjs = adjs0 + adjs1 + adjs2
  {
    int n4 = (int)(BNN / 4);
    add3_kernel<<<dim3((n4 + 255) / 256), dim3(256), 0, stream>>>(
        (const float4*)adjs0, (const float4*)adjs1, (const float4*)adjs2,
        (float4*)adjs, n4);
  }

  // 2) h0 = relu(BN_init(hs_init @ W_init))
  {
    GemmNFArgs a = {};
    a.A[0] = hs_init;
    a.X[0] = W_init;
    a.Cin[0] = nullptr;
    a.C[0] = h0;
    a.xbs = 0;
    a.bn_mean = bn_init_mean;
    a.bn_var = bn_init_var;
    a.bn_gamma = bn_init_gamma;
    a.bn_beta = bn_init_beta;
    gemm_nf_kernel<<<dim3(Nn / 32, Bn, 1), dim3(128), 0, stream>>>(a);
  }

  const float* adjk[3] = {adjs0, adjs1, adjs2};

  // layer 0: P_k[0] = adjs_k @ h0  (into Pa)
  {
    GemmNFArgs a = {};
    for (int k = 0; k < 3; ++k) {
      a.A[k] = adjk[k];
      a.X[k] = h0;
      a.Cin[k] = nullptr;
    }
    a.C[0] = Pa0; a.C[1] = Pa1; a.C[2] = Pa2;
    a.xbs = (long long)Nn * Fn;
    gemm_nf_kernel<<<dim3(Nn / 32, Bn, 3), dim3(128), 0, stream>>>(a);
  }
  layer_fuse_kernel<<<dim3(Bn * Nn / 4), dim3(256), 0, stream>>>(
      h0, Pa0, Pa1, Pa2, W3, W0, W1, W2, bvec, bn_layer_mean, bn_layer_var,
      bn_layer_gamma, bn_layer_beta, h1);

  // layer 1: g_k = adjs_k @ h1 ; P_k[1] = g_k + adjs @ P_k[0]  (into Pb)
  {
    GemmNFArgs a = {};
    for (int k = 0; k < 3; ++k) {
      a.A[k] = adjk[k];
      a.X[k] = h1;
      a.Cin[k] = nullptr;
    }
    a.C[0] = g0; a.C[1] = g1; a.C[2] = g2;
    a.xbs = (long long)Nn * Fn;
    gemm_nf_kernel<<<dim3(Nn / 32, Bn, 3), dim3(128), 0, stream>>>(a);
  }
  {
    GemmNFArgs a = {};
    a.A[0] = adjs; a.A[1] = adjs; a.A[2] = adjs;
    a.X[0] = Pa0; a.X[1] = Pa1; a.X[2] = Pa2;
    a.Cin[0] = g0; a.Cin[1] = g1; a.Cin[2] = g2;
    a.C[0] = Pb0; a.C[1] = Pb1; a.C[2] = Pb2;
    a.xbs = (long long)Nn * Fn;
    gemm_nf_kernel<<<dim3(Nn / 32, Bn, 3), dim3(128), 0, stream>>>(a);
  }
  layer_fuse_kernel<<<dim3(Bn * Nn / 4), dim3(256), 0, stream>>>(
      h1, Pb0, Pb1, Pb2, W3 + Fn * Fn, W0 + Fn * Fn, W1 + Fn * Fn,
      W2 + Fn * Fn, bvec + Fn, bn_layer_mean + Nn, bn_layer_var + Nn,
      bn_layer_gamma + Nn, bn_layer_beta + Nn, h2);

  // layer 2: g_k = adjs_k @ h2 ; P_k[2] = g_k + adjs @ P_k[1]  (into Pa)
  {
    GemmNFArgs a = {};
    for (int k = 0; k < 3; ++k) {
      a.A[k] = adjk[k];
      a.X[k] = h2;
      a.Cin[k] = nullptr;
    }
    a.C[0] = g0; a.C[1] = g1; a.C[2] = g2;
    a.xbs = (long long)Nn * Fn;
    gemm_nf_kernel<<<dim3(Nn / 32, Bn, 3), dim3(128), 0, stream>>>(a);
  }
  {
    GemmNFArgs a = {};
    a.A[0] = adjs; a.A[1] = adjs; a.A[2] = adjs;
    a.X[0] = Pb0; a.X[1] = Pb1; a.X[2] = Pb2;
    a.Cin[0] = g0; a.Cin[1] = g1; a.Cin[2] = g2;
    a.C[0] = Pa0; a.C[1] = Pa1; a.C[2] = Pa2;
    a.xbs = (long long)Nn * Fn;
    gemm_nf_kernel<<<dim3(Nn / 32, Bn, 3), dim3(128), 0, stream>>>(a);
  }
  layer_fuse_kernel<<<dim3(Bn * Nn / 4), dim3(256), 0, stream>>>(
      h2, Pa0, Pa1, Pa2, W3 + 2 * Fn * Fn, W0 + 2 * Fn * Fn, W1 + 2 * Fn * Fn,
      W2 + 2 * Fn * Fn, bvec + 2 * Fn, bn_layer_mean + 2 * Nn,
      bn_layer_var + 2 * Nn, bn_layer_gamma + 2 * Nn, bn_layer_beta + 2 * Nn,
      h3);

  // head
  graph_head_kernel<<<dim3(Bn), dim3(256), 0, stream>>>(
      h3, bn_graph_mean, bn_graph_var, bn_graph_gamma, bn_graph_beta, fc1_w,
      fc1_b, (float*)d_out);
}

// Round 2
// 187.105 us; speedup vs baseline: 1.3545x; 1.3545x over previous
//
#include <hip/hip_runtime.h>

typedef __attribute__((ext_vector_type(8))) short bf16x8;
typedef __attribute__((ext_vector_type(4))) float f32x4;
typedef __attribute__((ext_vector_type(8))) unsigned short u16x8;

constexpr int Bn = 16;
constexpr int Nn = 512;
constexpr int Fn = 64;
constexpr int Aout = 512;

static __device__ __forceinline__ unsigned short f2bf(float f) {
  union { float f; unsigned int u; } v; v.f = f;
  unsigned int r = v.u + 0x7fffu + ((v.u >> 16) & 1u);
  return (unsigned short)(r >> 16);
}
static __device__ __forceinline__ float bf2f(unsigned short u) {
  union { unsigned int u; float f; } v; v.u = ((unsigned int)u) << 16;
  return v.f;
}

// ---------------------------------------------------------------------------
// adjs0/1/2 fp32 -> bf16 x3 + bf16 sum. one float4 per thread.
// ---------------------------------------------------------------------------
__launch_bounds__(256)
__global__ void conv3_kernel(const float4* __restrict__ a0,
                             const float4* __restrict__ a1,
                             const float4* __restrict__ a2,
                             ushort4* __restrict__ o0,
                             ushort4* __restrict__ o1,
                             ushort4* __restrict__ o2,
                             ushort4* __restrict__ os) {
  size_t i = (size_t)blockIdx.x * 256 + threadIdx.x;
  float4 x = a0[i], y = a1[i], z = a2[i];
  ushort4 p;
  p.x = f2bf(x.x); p.y = f2bf(x.y); p.z = f2bf(x.z); p.w = f2bf(x.w);
  o0[i] = p;
  p.x = f2bf(y.x); p.y = f2bf(y.y); p.z = f2bf(y.z); p.w = f2bf(y.w);
  o1[i] = p;
  p.x = f2bf(z.x); p.y = f2bf(z.y); p.z = f2bf(z.z); p.w = f2bf(z.w);
  o2[i] = p;
  p.x = f2bf(x.x + y.x + z.x); p.y = f2bf(x.y + y.y + z.y);
  p.z = f2bf(x.z + y.z + z.z); p.w = f2bf(x.w + y.w + z.w);
  os[i] = p;
}

__launch_bounds__(256)
__global__ void convb_kernel(const float4* __restrict__ a,
                             ushort4* __restrict__ o) {
  size_t i = (size_t)blockIdx.x * 256 + threadIdx.x;
  float4 x = a[i];
  ushort4 p;
  p.x = f2bf(x.x); p.y = f2bf(x.y); p.z = f2bf(x.z); p.w = f2bf(x.w);
  o[i] = p;
}

// W_init [512][64] fp32 -> W_initT [64][512] bf16
__launch_bounds__(256)
__global__ void convWT_kernel(const float* __restrict__ W,
                              unsigned short* __restrict__ WT) {
  int o = blockIdx.x * 256 + threadIdx.x;  // 32768
  int f = o >> 9, k = o & 511;
  WT[o] = f2bf(W[k * Fn + f]);
}

// ---------------------------------------------------------------------------
// MFMA GEMM: outT[z][b] (64F x 512N, bf16) = sum_seg A_seg[z][b] @ X_seg[z][b]
// A: [512][512] bf16 row-major (K contiguous). X given transposed [64][512]
// (per-col K contiguous). Optional BN(+ReLU) over rows n. 256 thr = 4 waves,
// wave = 16 rows x 64 cols (4 col-tiles of mfma_f32_16x16x32_bf16).
// ---------------------------------------------------------------------------
struct MArgs {
  const unsigned short* A0[3];
  const unsigned short* A1[3];
  const unsigned short* X0[3];
  const unsigned short* X1[3];
  unsigned short* O[3];
  long long x0_bs, x1_bs;  // X batch strides (elements); A stride fixed 512*512
  int nseg;
  const float* mean; const float* var; const float* gamma; const float* beta;
};

__launch_bounds__(256)
__global__ void gemm_T_kernel(MArgs args) {
  const int z = blockIdx.z, b = blockIdx.y;
  const int t = threadIdx.x;
  const int wv = t >> 6, l = t & 63;
  const int lr = l & 15;            // A row / X col within tile
  const int lk = (l >> 4) << 3;     // k sub-offset (8 elems per lane group)
  const int R0 = blockIdx.x * 64 + wv * 16;

  f32x4 acc0 = {0.f, 0.f, 0.f, 0.f};
  f32x4 acc1 = acc0, acc2 = acc0, acc3 = acc0;

  for (int seg = 0; seg < args.nseg; ++seg) {
    const unsigned short* Ap = seg == 0 ? args.A0[z] : args.A1[z];
    const unsigned short* Xp = seg == 0 ? args.X0[z] : args.X1[z];
    const long long xbs = seg == 0 ? args.x0_bs : args.x1_bs;
    const unsigned short* A =
        Ap + ((size_t)b << 18) + ((size_t)(R0 + lr) << 9) + lk;
    const unsigned short* X = Xp + (size_t)b * xbs + ((size_t)lr << 9) + lk;
#pragma unroll 8
    for (int k0 = 0; k0 < 512; k0 += 32) {
      bf16x8 af = *(const bf16x8*)(A + k0);
      bf16x8 b0 = *(const bf16x8*)(X + k0);
      bf16x8 b1 = *(const bf16x8*)(X + 16 * 512 + k0);
      bf16x8 b2 = *(const bf16x8*)(X + 32 * 512 + k0);
      bf16x8 b3 = *(const bf16x8*)(X + 48 * 512 + k0);
      acc0 = __builtin_amdgcn_mfma_f32_16x16x32_bf16(af, b0, acc0, 0, 0, 0);
      acc1 = __builtin_amdgcn_mfma_f32_16x16x32_bf16(af, b1, acc1, 0, 0, 0);
      acc2 = __builtin_amdgcn_mfma_f32_16x16x32_bf16(af, b2, acc2, 0, 0, 0);
      acc3 = __builtin_amdgcn_mfma_f32_16x16x32_bf16(af, b3, acc3, 0, 0, 0);
    }
  }

  unsigned short* Ob = args.O[z] + ((size_t)b << 15);
  const int rbase = R0 + ((l >> 4) << 2);  // 4 consecutive output rows
  float sc[4], mu[4], bt[4];
  const bool hasbn = args.mean != nullptr;
  if (hasbn) {
#pragma unroll
    for (int i = 0; i < 4; ++i) {
      int n = rbase + i;
      sc[i] = rsqrtf(args.var[n] + 1e-5f) * args.gamma[n];
      mu[i] = args.mean[n];
      bt[i] = args.beta[n];
    }
  }
  f32x4 accs[4] = {acc0, acc1, acc2, acc3};
#pragma unroll
  for (int c = 0; c < 4; ++c) {
    int col = c * 16 + lr;
    ushort4 w;
#pragma unroll
    for (int i = 0; i < 4; ++i) {
      float v = accs[c][i];
      if (hasbn) v = fmaxf(fmaf(v - mu[i], sc[i], bt[i]), 0.f);
      ((unsigned short*)&w)[i] = f2bf(v);
    }
    *(ushort4*)(Ob + ((size_t)col << 9) + rbase) = w;
  }
}

// ---------------------------------------------------------------------------
// h_nextT = bf16( relu(BN_l( h@W3 + b + P0@W0 + P1@W1 + P2@W2 )) ), all
// inputs transposed bf16 [64][512] per b. Block: (b, 16 n-cols), 256 thr.
// ---------------------------------------------------------------------------
__launch_bounds__(256)
__global__ void fuse_T_kernel(const unsigned short* __restrict__ hT,
                              const unsigned short* __restrict__ P0T,
                              const unsigned short* __restrict__ P1T,
                              const unsigned short* __restrict__ P2T,
                              const float* __restrict__ W3,
                              const float* __restrict__ W0,
                              const float* __restrict__ W1,
                              const float* __restrict__ W2,
                              const float* __restrict__ bias,
                              const float* __restrict__ mean,
                              const float* __restrict__ var,
                              const float* __restrict__ gamma,
                              const float* __restrict__ beta,
                              unsigned short* __restrict__ outT) {
  const int b = blockIdx.y;
  const int n0 = blockIdx.x * 16;
  const int t = threadIdx.x;
  __shared__ __align__(16) unsigned short lds[4][64][16];
  {
    const int mat = t >> 6, k = t & 63;
    const unsigned short* srcs[4] = {hT, P0T, P1T, P2T};
    const unsigned short* s = srcs[mat] + ((size_t)b << 15) + ((size_t)k << 9) + n0;
    *(uint4*)&lds[mat][k][0] = *(const uint4*)s;
    *(uint4*)&lds[mat][k][8] = *(const uint4*)(s + 8);
  }
  __syncthreads();
  const int fo = t & 63, g = t >> 6;
  float acc[4];
#pragma unroll
  for (int i = 0; i < 4; ++i) acc[i] = bias[fo];
  const float* Ws[4] = {W3, W0, W1, W2};
  for (int mat = 0; mat < 4; ++mat) {
    const float* __restrict__ W = Ws[mat];
#pragma unroll 8
    for (int k = 0; k < 64; ++k) {
      float w = W[k * 64 + fo];
#pragma unroll
      for (int i = 0; i < 4; ++i)
        acc[i] = fmaf(bf2f(lds[mat][k][g * 4 + i]), w, acc[i]);
    }
  }
  ushort4 o;
#pragma unroll
  for (int i = 0; i < 4; ++i) {
    int n = n0 + g * 4 + i;
    float sc = rsqrtf(var[n] + 1e-5f) * gamma[n];
    float v = fmaf(acc[i] - mean[n], sc, beta[n]);
    ((unsigned short*)&o)[i] = f2bf(fmaxf(v, 0.f));
  }
  *(ushort4*)(outT + ((size_t)b << 15) + ((size_t)fo << 9) + n0 + g * 4) = o;
}

// ---------------------------------------------------------------------------
// head: sum over n (contiguous in h3T), BN+ReLU, FC 512, softmax. block per b.
// ---------------------------------------------------------------------------
__launch_bounds__(256)
__global__ void head_T_kernel(const unsigned short* __restrict__ h3T,
                              const float* __restrict__ gmean,
                              const float* __restrict__ gvar,
                              const float* __restrict__ ggamma,
                              const float* __restrict__ gbeta,
                              const float* __restrict__ fc_w,
                              const float* __restrict__ fc_b,
                              float* __restrict__ out) {
  const int b = blockIdx.x;
  const int t = threadIdx.x;
  __shared__ float part[256];
  __shared__ float gh[64];
  __shared__ float red[256];

  const int f = t >> 2, q = t & 3;
  const unsigned short* hp = h3T + ((size_t)b << 15) + ((size_t)f << 9) + q * 128;
  float s = 0.f;
#pragma unroll
  for (int j = 0; j < 16; ++j) {
    u16x8 v = *(const u16x8*)(hp + j * 8);
#pragma unroll
    for (int e = 0; e < 8; ++e) s += bf2f((unsigned short)v[e]);
  }
  part[t] = s;
  __syncthreads();
  if (t < 64) {
    float sum = part[t * 4] + part[t * 4 + 1] + part[t * 4 + 2] + part[t * 4 + 3];
    float sc = rsqrtf(gvar[t] + 1e-5f) * ggamma[t];
    float v = fmaf(sum - gmean[t], sc, gbeta[t]);
    gh[t] = v > 0.f ? v : 0.f;
  }
  __syncthreads();

  float lg[2];
#pragma unroll
  for (int rep = 0; rep < 2; ++rep) {
    const int a = t + rep * 256;
    const float* __restrict__ w = fc_w + (size_t)a * Fn;
    float acc = fc_b[a];
#pragma unroll 8
    for (int kk = 0; kk < 64; ++kk) acc = fmaf(gh[kk], w[kk], acc);
    lg[rep] = acc;
  }
  red[t] = fmaxf(lg[0], lg[1]);
  __syncthreads();
  for (int off = 128; off > 0; off >>= 1) {
    if (t < off) red[t] = fmaxf(red[t], red[t + off]);
    __syncthreads();
  }
  const float mx = red[0];
  __syncthreads();
  const float e0 = __expf(lg[0] - mx), e1 = __expf(lg[1] - mx);
  red[t] = e0 + e1;
  __syncthreads();
  for (int off = 128; off > 0; off >>= 1) {
    if (t < off) red[t] += red[t + off];
    __syncthreads();
  }
  const float inv = 1.f / red[0];
  out[(size_t)b * Aout + t] = e0 * inv;
  out[(size_t)b * Aout + t + 256] = e1 * inv;
}

// ---------------------------------------------------------------------------
extern "C" void kernel_launch(void* const* d_in, const int* in_sizes, int n_in,
                              void* d_out, int out_size, void* d_ws,
                              size_t ws_size, hipStream_t stream) {
  (void)in_sizes; (void)n_in; (void)out_size; (void)ws_size;
  const float* hs_init = (const float*)d_in[0];
  const float* adjs0 = (const float*)d_in[1];
  const float* adjs1 = (const float*)d_in[2];
  const float* adjs2 = (const float*)d_in[3];
  const float* W_init = (const float*)d_in[4];
  const float* W0 = (const float*)d_in[5];
  const float* W1 = (const float*)d_in[6];
  const float* W2 = (const float*)d_in[7];
  const float* W3 = (const float*)d_in[8];
  const float* bvec = (const float*)d_in[9];
  const float* fc1_w = (const float*)d_in[10];
  const float* fc1_b = (const float*)d_in[11];
  const float* bn_init_mean = (const float*)d_in[12];
  const float* bn_init_var = (const float*)d_in[13];
  const float* bn_init_gamma = (const float*)d_in[14];
  const float* bn_init_beta = (const float*)d_in[15];
  const float* bn_layer_mean = (const float*)d_in[16];
  const float* bn_layer_var = (const float*)d_in[17];
  const float* bn_layer_gamma = (const float*)d_in[18];
  const float* bn_layer_beta = (const float*)d_in[19];
  const float* bn_graph_mean = (const float*)d_in[20];
  const float* bn_graph_var = (const float*)d_in[21];
  const float* bn_graph_gamma = (const float*)d_in[22];
  const float* bn_graph_beta = (const float*)d_in[23];

  const size_t ADJ = (size_t)Bn * Nn * Nn;  // 4,194,304 elems
  const size_t NF = (size_t)Bn * Fn * Nn;   // 524,288 elems

  unsigned short* W = (unsigned short*)d_ws;
  unsigned short* adjsb = W;             // sum
  unsigned short* a0b = W + ADJ;
  unsigned short* a1b = W + 2 * ADJ;
  unsigned short* a2b = W + 3 * ADJ;
  unsigned short* WiT = W + 4 * ADJ;     // 32768
  unsigned short* h0T = WiT + 32768;
  unsigned short* h3T = h0T;             // alias: h0T dead before fuse3 writes
  unsigned short* h1T = h0T + NF;
  unsigned short* h2T = h1T + NF;
  unsigned short* Pa0 = h2T + NF;
  unsigned short* Pa1 = Pa0 + NF;
  unsigned short* Pa2 = Pa1 + NF;
  unsigned short* Pb0 = Pa2 + NF;
  unsigned short* Pb1 = Pb0 + NF;
  unsigned short* Pb2 = Pb1 + NF;
  unsigned short* hsb = h1T;             // alias: spans 8*NF, all written later

  // converts
  conv3_kernel<<<dim3((unsigned)(ADJ / 4 / 256)), dim3(256), 0, stream>>>(
      (const float4*)adjs0, (const float4*)adjs1, (const float4*)adjs2,
      (ushort4*)a0b, (ushort4*)a1b, (ushort4*)a2b, (ushort4*)adjsb);
  convb_kernel<<<dim3((unsigned)(ADJ / 4 / 256)), dim3(256), 0, stream>>>(
      (const float4*)hs_init, (ushort4*)hsb);
  convWT_kernel<<<dim3(128), dim3(256), 0, stream>>>(W_init, WiT);

  const long long nfb = (long long)Fn * Nn;  // 32768

  // h0 = relu(BN_init(hs_init @ W_init))   (outputs h0T)
  {
    MArgs a = {};
    a.A0[0] = hsb; a.X0[0] = WiT; a.O[0] = h0T;
    a.x0_bs = 0; a.nseg = 1;
    a.mean = bn_init_mean; a.var = bn_init_var;
    a.gamma = bn_init_gamma; a.beta = bn_init_beta;
    gemm_T_kernel<<<dim3(8, Bn, 1), dim3(256), 0, stream>>>(a);
  }

  const unsigned short* akb[3] = {a0b, a1b, a2b};

  // layer 0: Pa_k = adjs_k @ h0
  {
    MArgs a = {};
    unsigned short* O[3] = {Pa0, Pa1, Pa2};
    for (int k = 0; k < 3; ++k) { a.A0[k] = akb[k]; a.X0[k] = h0T; a.O[k] = O[k]; }
    a.x0_bs = nfb; a.nseg = 1;
    gemm_T_kernel<<<dim3(8, Bn, 3), dim3(256), 0, stream>>>(a);
  }
  fuse_T_kernel<<<dim3(32, Bn), dim3(256), 0, stream>>>(
      h0T, Pa0, Pa1, Pa2, W3, W0, W1, W2, bvec, bn_layer_mean, bn_layer_var,
      bn_layer_gamma, bn_layer_beta, h1T);

  // layer 1: Pb_k = adjs_k @ h1 + adjs @ Pa_k   (fused K=1024)
  {
    MArgs a = {};
    unsigned short* O[3] = {Pb0, Pb1, Pb2};
    const unsigned short* Xs[3] = {Pa0, Pa1, Pa2};
    for (int k = 0; k < 3; ++k) {
      a.A0[k] = akb[k]; a.X0[k] = h1T;
      a.A1[k] = adjsb; a.X1[k] = Xs[k]; a.O[k] = O[k];
    }
    a.x0_bs = nfb; a.x1_bs = nfb; a.nseg = 2;
    gemm_T_kernel<<<dim3(8, Bn, 3), dim3(256), 0, stream>>>(a);
  }
  fuse_T_kernel<<<dim3(32, Bn), dim3(256), 0, stream>>>(
      h1T, Pb0, Pb1, Pb2, W3 + Fn * Fn, W0 + Fn * Fn, W1 + Fn * Fn,
      W2 + Fn * Fn, bvec + Fn, bn_layer_mean + Nn, bn_layer_var + Nn,
      bn_layer_gamma + Nn, bn_layer_beta + Nn, h2T);

  // layer 2: Pa_k = adjs_k @ h2 + adjs @ Pb_k
  {
    MArgs a = {};
    unsigned short* O[3] = {Pa0, Pa1, Pa2};
    const unsigned short* Xs[3] = {Pb0, Pb1, Pb2};
    for (int k = 0; k < 3; ++k) {
      a.A0[k] = akb[k]; a.X0[k] = h2T;
      a.A1[k] = adjsb; a.X1[k] = Xs[k]; a.O[k] = O[k];
    }
    a.x0_bs = nfb; a.x1_bs = nfb; a.nseg = 2;
    gemm_T_kernel<<<dim3(8, Bn, 3), dim3(256), 0, stream>>>(a);
  }
  fuse_T_kernel<<<dim3(32, Bn), dim3(256), 0, stream>>>(
      h2T, Pa0, Pa1, Pa2, W3 + 2 * Fn * Fn, W0 + 2 * Fn * Fn,
      W1 + 2 * Fn * Fn, W2 + 2 * Fn * Fn, bvec + 2 * Fn,
      bn_layer_mean + 2 * Nn, bn_layer_var + 2 * Nn, bn_layer_gamma + 2 * Nn,
      bn_layer_beta + 2 * Nn, h3T);

  head_T_kernel<<<dim3(Bn), dim3(256), 0, stream>>>(
      h3T, bn_graph_mean, bn_graph_var, bn_graph_gamma, bn_graph_beta, fc1_w,
      fc1_b, (float*)d_out);
}